// Round 2
// baseline (21595.229 us; speedup 1.0000x reference)
//
#include <hip/hip_runtime.h>
#include <stdint.h>

// ---------------------------------------------------------------------------
// RnnSampler: 128 sequential steps of {MLP policy head -> gumbel-max sample ->
// embed -> LSTM cell}. Reproduces JAX threefry PRNG in PARTITIONABLE mode
// (jax_threefry_partitionable=True, the modern default):
//   split:  key_t = threefry2x32(k0,k1, 0, t)            -> (o0, o1)
//   bits:   bits[p] = xor(threefry2x32(key, 0, p))       p = flat index
// N=256 samples, E=256, V=32000, steps=128.
// ---------------------------------------------------------------------------

#define STEPS 128
#define NS    256
#define EDIM  256
#define VDIM  32000

// Threefry-2x32, 20 rounds (Random123 / JAX-compatible)
__host__ __device__ __forceinline__ void tf2x32(uint32_t k0, uint32_t k1,
                                                uint32_t c0, uint32_t c1,
                                                uint32_t& o0, uint32_t& o1) {
  const uint32_t ks2 = k0 ^ k1 ^ 0x1BD11BDAu;
  uint32_t x0 = c0 + k0, x1 = c1 + k1;
#define TF_R(r) { x0 += x1; x1 = (x1 << (r)) | (x1 >> (32 - (r))); x1 ^= x0; }
  TF_R(13) TF_R(15) TF_R(26) TF_R(6)
  x0 += k1;  x1 += ks2 + 1u;
  TF_R(17) TF_R(29) TF_R(16) TF_R(24)
  x0 += ks2; x1 += k0 + 2u;
  TF_R(13) TF_R(15) TF_R(26) TF_R(6)
  x0 += k0;  x1 += k1 + 3u;
  TF_R(17) TF_R(29) TF_R(16) TF_R(24)
  x0 += k1;  x1 += ks2 + 4u;
  TF_R(13) TF_R(15) TF_R(26) TF_R(6)
  x0 += ks2; x1 += k0 + 5u;
#undef TF_R
  o0 = x0; o1 = x1;
}

// ---------------------------------------------------------------------------
// Generic fp32 GEMM: C[M,N] = act(A[M,K] * B[N,K]^T + bias), tiles TILExTILE.
// ---------------------------------------------------------------------------
template<int TILE, bool RELU>
__global__ __launch_bounds__(256) void k_gemm(
    const float* __restrict__ A, int lda,
    const float* __restrict__ B, int ldb,
    const float* __restrict__ bias,
    float* __restrict__ C, int ldc, int K)
{
  constexpr int TM = TILE / 16;
  __shared__ float At[16][TILE + 4];
  __shared__ float Bt[16][TILE + 4];
  const int tid = threadIdx.x;
  const int tx = tid & 15, ty = tid >> 4;
  const int n0 = blockIdx.y * TILE;   // row (M) offset
  const int v0 = blockIdx.x * TILE;   // col (N) offset
  float acc[TM][TM] = {};

  for (int kk = 0; kk < K; kk += 16) {
#pragma unroll
    for (int i = 0; i < TILE / 64; i++) {
      int id = tid * (TILE / 64) + i;
      int r = id >> 2, c4 = (id & 3) << 2;
      float4 a = *(const float4*)(A + (size_t)(n0 + r) * lda + kk + c4);
      float4 b = *(const float4*)(B + (size_t)(v0 + r) * ldb + kk + c4);
      At[c4 + 0][r] = a.x; At[c4 + 1][r] = a.y; At[c4 + 2][r] = a.z; At[c4 + 3][r] = a.w;
      Bt[c4 + 0][r] = b.x; Bt[c4 + 1][r] = b.y; Bt[c4 + 2][r] = b.z; Bt[c4 + 3][r] = b.w;
    }
    __syncthreads();
#pragma unroll
    for (int k = 0; k < 16; k++) {
      float af[TM], bf[TM];
#pragma unroll
      for (int m = 0; m < TM; m += 4) {
        *(float4*)&af[m] = *(const float4*)&At[k][ty * TM + m];
        *(float4*)&bf[m] = *(const float4*)&Bt[k][tx * TM + m];
      }
#pragma unroll
      for (int a = 0; a < TM; a++)
#pragma unroll
        for (int b = 0; b < TM; b++)
          acc[a][b] = fmaf(af[a], bf[b], acc[a][b]);
    }
    __syncthreads();
  }
#pragma unroll
  for (int a = 0; a < TM; a++) {
    int r = n0 + ty * TM + a;
#pragma unroll
    for (int b = 0; b < TM; b++) {
      int v = v0 + tx * TM + b;
      float x = acc[a][b] + bias[v];
      if (RELU) x = fmaxf(x, 0.0f);
      C[(size_t)r * ldc + v] = x;
    }
  }
}

// ---------------------------------------------------------------------------
// Logits GEMM (128x128 tile, K=512) fused with gumbel noise + per-row argmax
// partial reduction. part[row * 250 + vchunk] = packed (orderedFloat, ~idx).
// ---------------------------------------------------------------------------
__global__ __launch_bounds__(256) void k_logits(
    const float* __restrict__ A,      // hidden [256][512]
    const float* __restrict__ B,      // W2 [32000][512]
    const float* __restrict__ bias,   // b2 [32000]
    unsigned long long* __restrict__ part,
    uint32_t key0, uint32_t key1)
{
  __shared__ float At[16][132];
  __shared__ float Bt[16][132];
  __shared__ unsigned long long red[128][16];
  const int tid = threadIdx.x;
  const int tx = tid & 15, ty = tid >> 4;
  const int v0 = blockIdx.x * 128;
  const int n0 = blockIdx.y * 128;
  float acc[8][8] = {};

  for (int kk = 0; kk < 512; kk += 16) {
#pragma unroll
    for (int i = 0; i < 2; i++) {
      int id = tid * 2 + i;
      int r = id >> 2, c4 = (id & 3) << 2;
      float4 a = *(const float4*)(A + (size_t)(n0 + r) * 512 + kk + c4);
      float4 b = *(const float4*)(B + (size_t)(v0 + r) * 512 + kk + c4);
      At[c4 + 0][r] = a.x; At[c4 + 1][r] = a.y; At[c4 + 2][r] = a.z; At[c4 + 3][r] = a.w;
      Bt[c4 + 0][r] = b.x; Bt[c4 + 1][r] = b.y; Bt[c4 + 2][r] = b.z; Bt[c4 + 3][r] = b.w;
    }
    __syncthreads();
#pragma unroll
    for (int k = 0; k < 16; k++) {
      float af[8], bf[8];
      *(float4*)&af[0] = *(const float4*)&At[k][ty * 8];
      *(float4*)&af[4] = *(const float4*)&At[k][ty * 8 + 4];
      *(float4*)&bf[0] = *(const float4*)&Bt[k][tx * 8];
      *(float4*)&bf[4] = *(const float4*)&Bt[k][tx * 8 + 4];
#pragma unroll
      for (int a = 0; a < 8; a++)
#pragma unroll
        for (int b = 0; b < 8; b++)
          acc[a][b] = fmaf(af[a], bf[b], acc[a][b]);
    }
    __syncthreads();
  }

  // epilogue: per-element gumbel noise + per-row running argmax.
  // partitionable-mode bits: counter = (0, p) with p = r*32000+v; bits = o0^o1
#pragma unroll
  for (int a = 0; a < 8; a++) {
    const int r = n0 + ty * 8 + a;
    unsigned long long best = 0ull;
#pragma unroll
    for (int b = 0; b < 8; b++) {
      const int v = v0 + tx * 8 + b;
      const uint32_t p = (uint32_t)r * 32000u + (uint32_t)v;
      uint32_t o0, o1;
      tf2x32(key0, key1, 0u, p, o0, o1);
      const uint32_t bits = o0 ^ o1;
      // JAX uniform: bitcast(bits>>9 | 0x3f800000) - 1, clamped to tiny
      float f = __uint_as_float((bits >> 9) | 0x3f800000u) - 1.0f;
      float u = fmaxf(f, 1.17549435e-38f);
      float g = -logf(-logf(u));
      float val = acc[a][b] + bias[v] + g;
      uint32_t uv = __float_as_uint(val);
      uv = (uv & 0x80000000u) ? ~uv : (uv | 0x80000000u);  // order-preserving
      unsigned long long pk =
          ((unsigned long long)uv << 32) |
          (unsigned long long)(0xFFFFFFFFu - (uint32_t)v);  // tie -> lowest v
      best = (pk > best) ? pk : best;
    }
    red[ty * 8 + a][tx] = best;
  }
  __syncthreads();
  if (tid < 128) {
    unsigned long long best = 0ull;
#pragma unroll
    for (int i = 0; i < 16; i++) {
      unsigned long long x = red[tid][i];
      best = (x > best) ? x : best;
    }
    part[(size_t)(n0 + tid) * 250 + blockIdx.x] = best;
  }
}

// Per-row final reduction over 250 partials -> token; write out + gather embed
__global__ __launch_bounds__(256) void k_sample(
    const unsigned long long* __restrict__ part,
    const float* __restrict__ token_embed,
    int* __restrict__ out, float* __restrict__ xh, int t)
{
  __shared__ unsigned long long sm[256];
  const int row = blockIdx.x, tid = threadIdx.x;
  sm[tid] = (tid < 250) ? part[(size_t)row * 250 + tid] : 0ull;
  __syncthreads();
  for (int s = 128; s > 0; s >>= 1) {
    if (tid < s) {
      unsigned long long o = sm[tid + s];
      if (o > sm[tid]) sm[tid] = o;
    }
    __syncthreads();
  }
  const int token = (int)(0xFFFFFFFFu - (uint32_t)(sm[0] & 0xFFFFFFFFu));
  if (tid == 0) out[(size_t)row * STEPS + t] = token;
  // gather embedding row into xh[:, 0:256]
  xh[(size_t)row * 512 + tid] = token_embed[(size_t)token * EDIM + tid];
}

// LSTM elementwise update: gates [256][1024] (i|f|g|o), c [256][256],
// h written to xh[:, 256:512]
__global__ __launch_bounds__(256) void k_update(
    const float* __restrict__ gates, float* __restrict__ c,
    float* __restrict__ xh)
{
  const int n = blockIdx.x, e = threadIdx.x;
  const float* g = gates + (size_t)n * 1024;
  const float gi = g[e], gf = g[256 + e], gg = g[512 + e], go = g[768 + e];
  const float si = 1.0f / (1.0f + expf(-gi));
  const float sf = 1.0f / (1.0f + expf(-gf));
  const float so = 1.0f / (1.0f + expf(-go));
  float cv = sf * c[(size_t)n * 256 + e] + si * tanhf(gg);
  c[(size_t)n * 256 + e] = cv;
  xh[(size_t)n * 512 + 256 + e] = so * tanhf(cv);
}

__global__ __launch_bounds__(256) void k_init(
    float* __restrict__ xh, float* __restrict__ c,
    const float* __restrict__ init_h)
{
  const int n = blockIdx.x, e = threadIdx.x;
  const float v = init_h[e];
  xh[(size_t)n * 512 + 256 + e] = v;
  c[(size_t)n * 256 + e] = v;
}

// Build Wcat = [W_ih | W_hh] (1024 x 512) and bcat = b_ih + b_hh
__global__ __launch_bounds__(256) void k_prep(
    float* __restrict__ Wcat, float* __restrict__ bcat,
    const float* __restrict__ W_ih, const float* __restrict__ W_hh,
    const float* __restrict__ b_ih, const float* __restrict__ b_hh)
{
  const int q = blockIdx.x, e = threadIdx.x;
  Wcat[(size_t)q * 512 + e]       = W_ih[(size_t)q * 256 + e];
  Wcat[(size_t)q * 512 + 256 + e] = W_hh[(size_t)q * 256 + e];
  if (e == 0) bcat[q] = b_ih[q] + b_hh[q];
}

extern "C" void kernel_launch(void* const* d_in, const int* in_sizes, int n_in,
                              void* d_out, int out_size, void* d_ws, size_t ws_size,
                              hipStream_t stream) {
  const float* init_h      = (const float*)d_in[2];
  const float* token_embed = (const float*)d_in[3];
  const float* W_ih        = (const float*)d_in[4];
  const float* W_hh        = (const float*)d_in[5];
  const float* b_ih        = (const float*)d_in[6];
  const float* b_hh        = (const float*)d_in[7];
  const float* W1          = (const float*)d_in[8];
  const float* b1          = (const float*)d_in[9];
  const float* W2          = (const float*)d_in[10];
  const float* b2          = (const float*)d_in[11];
  int* out = (int*)d_out;

  // workspace carve (all offsets 16B-aligned)
  char* ws = (char*)d_ws;
  float* xh      = (float*)(ws + 0);            // [256][512]  x | h
  float* c       = (float*)(ws + 524288);       // [256][256]
  float* hidden  = (float*)(ws + 786432);       // [256][512]
  float* gates   = (float*)(ws + 1310720);      // [256][1024]
  float* Wcat    = (float*)(ws + 2359296);      // [1024][512]
  float* bcat    = (float*)(ws + 4456448);      // [1024]
  unsigned long long* part = (unsigned long long*)(ws + 4460544); // [256][250]

  // Host-side JAX key schedule, PARTITIONABLE (foldlike) split:
  // keys[t] = threefry2x32(0, 42, c0=0, c1=t) -> (o0, o1)
  uint32_t k0[STEPS], k1[STEPS];
  for (uint32_t t = 0; t < STEPS; t++) tf2x32(0u, 42u, 0u, t, k0[t], k1[t]);

  k_init<<<NS, 256, 0, stream>>>(xh, c, init_h);
  k_prep<<<1024, 256, 0, stream>>>(Wcat, bcat, W_ih, W_hh, b_ih, b_hh);

  for (int t = 0; t < STEPS; t++) {
    // hidden = relu(h @ W1^T + b1): M=256, N=512, K=256
    k_gemm<64, true><<<dim3(8, 4), 256, 0, stream>>>(
        xh + 256, 512, W1, 256, b1, hidden, 512, 256);
    // logits + gumbel + argmax partials: M=256, N=32000, K=512
    k_logits<<<dim3(250, 2), 256, 0, stream>>>(
        hidden, W2, b2, part, k0[t], k1[t]);
    // reduce partials -> token -> out + embedding gather into xh[:,0:256]
    k_sample<<<NS, 256, 0, stream>>>(part, token_embed, out, xh, t);
    // gates = [x|h] @ Wcat^T + bcat: M=256, N=1024, K=512
    k_gemm<64, false><<<dim3(16, 4), 256, 0, stream>>>(
        xh, 512, Wcat, 512, bcat, gates, 1024, 512);
    // LSTM state update
    k_update<<<NS, 256, 0, stream>>>(gates, c, xh);
  }
}